// Round 1
// baseline (515.354 us; speedup 1.0000x reference)
//
#include <hip/hip_runtime.h>

typedef unsigned short u16;
typedef __attribute__((ext_vector_type(4))) float f32x4;
typedef __attribute__((ext_vector_type(8))) short short8;

#define BB   2
#define SQL  2048
#define SKVL 4096
#define DM   1024
#define NH   16
#define DK   64

__device__ __forceinline__ u16 f2bf(float f) {
  union { float f; unsigned u; } v; v.f = f;
  unsigned r = v.u + 0x7fff + ((v.u >> 16) & 1);   // RNE
  return (u16)(r >> 16);
}

// async global->LDS, 16B per lane. lds base must be wave-uniform; HW scatters lane i to base + i*16.
__device__ __forceinline__ void gload16(const void* g, void* lds) {
  __builtin_amdgcn_global_load_lds(
      (const __attribute__((address_space(1))) unsigned int*)g,
      (__attribute__((address_space(3))) unsigned int*)lds, 16, 0, 0);
}

// ---------------- RMSNorm: fp32 in -> bf16 out ----------------
__global__ void rmsnorm_kernel(const float* __restrict__ x, const float* __restrict__ w,
                               u16* __restrict__ out) {
  int row = blockIdx.x;
  int t = threadIdx.x;
  float4 v = ((const float4*)(x + (size_t)row * DM))[t];
  float ss = v.x * v.x + v.y * v.y + v.z * v.z + v.w * v.w;
#pragma unroll
  for (int m = 32; m >= 1; m >>= 1) ss += __shfl_xor(ss, m, 64);
  __shared__ float red[4];
  int lane = t & 63, wv = t >> 6;
  if (lane == 0) red[wv] = ss;
  __syncthreads();
  float total = red[0] + red[1] + red[2] + red[3];
  float scale = rsqrtf(total * (1.0f / DM) + 1e-6f);
  float4 g = ((const float4*)w)[t];
  ushort4 o;
  o.x = f2bf(v.x * scale * g.x);
  o.y = f2bf(v.y * scale * g.y);
  o.z = f2bf(v.z * scale * g.z);
  o.w = f2bf(v.w * scale * g.w);
  ((ushort4*)(out + (size_t)row * DM))[t] = o;
}

// ---------------- fp32 -> bf16 elementwise ----------------
__global__ void cvt_kernel(const float* __restrict__ in, u16* __restrict__ out) {
  int i = blockIdx.x * 256 + threadIdx.x;
  float4 v = ((const float4*)in)[i];
  ushort4 o;
  o.x = f2bf(v.x); o.y = f2bf(v.y); o.z = f2bf(v.z); o.w = f2bf(v.w);
  ((ushort4*)out)[i] = o;
}

// ---------------- W[k][n] fp32 -> Wt[n][k] bf16 (32x32 LDS tile) ----------------
__global__ void tcvt_kernel(const float* __restrict__ W, u16* __restrict__ Wt) {
  __shared__ float tile[32][33];
  int tx = threadIdx.x & 31, ty = threadIdx.x >> 5;  // ty 0..7
  int k0 = blockIdx.y * 32, n0 = blockIdx.x * 32;
#pragma unroll
  for (int i = 0; i < 4; i++)
    tile[ty + i * 8][tx] = W[(size_t)(k0 + ty + i * 8) * DM + n0 + tx];
  __syncthreads();
#pragma unroll
  for (int i = 0; i < 4; i++)
    Wt[(size_t)(n0 + ty + i * 8) * DM + k0 + tx] = f2bf(tile[tx][ty + i * 8]);
}

// ---------------- 128x128 GEMM, A[M][1024] bf16 x Bt[N][1024] bf16 ----------------
// MODE 0: C bf16 [M][N].  MODE 1: V^T write: C bf16 [B][NH][DK][SKV].  MODE 2: C f32 = resid + acc.
template <int MODE>
__global__ void gemm_kernel(const u16* __restrict__ A, const u16* __restrict__ Bt,
                            void* __restrict__ C, const float* __restrict__ resid, int N) {
  const int K = 1024;
  __shared__ __align__(16) u16 Al[128 * 32];
  __shared__ __align__(16) u16 Bl[128 * 32];
  int tid = threadIdx.x, lane = tid & 63, w = tid >> 6;
  int l15 = lane & 15, quad = lane >> 4;
  int wy = w >> 1, wx = w & 1;
  int tm = blockIdx.x * 128, tn = blockIdx.y * 128;
  f32x4 acc[4][4] = {};

  for (int k0 = 0; k0 < K; k0 += 32) {
    __syncthreads();
#pragma unroll
    for (int r = 0; r < 2; r++) {
      int mg = w * 2 + r;
      gload16(A + (size_t)(tm + mg * 16 + l15) * K + k0 + quad * 8, &Al[mg * 512]);
      gload16(Bt + (size_t)(tn + mg * 16 + l15) * K + k0 + quad * 8, &Bl[mg * 512]);
    }
    __syncthreads();
    short8 af[4], bfr[4];
#pragma unroll
    for (int i = 0; i < 4; i++) {
      af[i] = *(const short8*)&Al[((wy * 4 + i) * 64 + lane) * 8];
      bfr[i] = *(const short8*)&Bl[((wx * 4 + i) * 64 + lane) * 8];
    }
#pragma unroll
    for (int mt = 0; mt < 4; mt++)
#pragma unroll
      for (int nt = 0; nt < 4; nt++)
        acc[mt][nt] = __builtin_amdgcn_mfma_f32_16x16x32_bf16(af[mt], bfr[nt], acc[mt][nt], 0, 0, 0);
  }

#pragma unroll
  for (int mt = 0; mt < 4; mt++) {
    int m0 = tm + wy * 64 + mt * 16 + quad * 4;
#pragma unroll
    for (int nt = 0; nt < 4; nt++) {
      int n = tn + wx * 64 + nt * 16 + l15;
      if (MODE == 0) {
#pragma unroll
        for (int r = 0; r < 4; r++)
          ((u16*)C)[(size_t)(m0 + r) * N + n] = f2bf(acc[mt][nt][r]);
      } else if (MODE == 1) {
        int b = m0 >> 12, skv = m0 & 4095;  // rows are b*SKV + skv
        int h = n >> 6, d = n & 63;
        ushort4 o;
        o.x = f2bf(acc[mt][nt][0]); o.y = f2bf(acc[mt][nt][1]);
        o.z = f2bf(acc[mt][nt][2]); o.w = f2bf(acc[mt][nt][3]);
        *(ushort4*)((u16*)C + (size_t)((b * NH + h) * DK + d) * SKVL + skv) = o;
      } else {
#pragma unroll
        for (int r = 0; r < 4; r++) {
          size_t idx = (size_t)(m0 + r) * N + n;
          ((float*)C)[idx] = resid[idx] + acc[mt][nt][r];
        }
      }
    }
  }
}

// ---------------- flash attention ----------------
// grid: (SQ/128, B*NH). block 256 = 4 waves; wave w owns 32 q-rows. KV tile = 64.
__global__ __launch_bounds__(256, 2) void flash_kernel(
    const u16* __restrict__ Q, const u16* __restrict__ Kb, const u16* __restrict__ Vt,
    const float* __restrict__ mask, u16* __restrict__ ctx) {
  __shared__ __align__(16) u16 Kl[64 * 64];      // [nt4][kf2][quad4][16][8]
  __shared__ __align__(16) u16 Vl[64 * 64];      // [dt4][kf2][quad4][16][8]
  __shared__ __align__(16) u16 Pl[4][32 * 64];   // per-wave, A-layout [mt2][kf2][quad4][16][8]
  int tid = threadIdx.x, lane = tid & 63, w = tid >> 6;
  int l15 = lane & 15, quad = lane >> 4;
  int qb = blockIdx.x, bh = blockIdx.y;
  int b = bh >> 4, h = bh & 15;
  const float LOG2E = 1.44269504f;

  short8 qf[2][2];
#pragma unroll
  for (int mt = 0; mt < 2; mt++)
#pragma unroll
    for (int kf = 0; kf < 2; kf++) {
      int q = qb * 128 + w * 32 + mt * 16 + l15;
      qf[mt][kf] = *(const short8*)(Q + (size_t)(b * SQL + q) * DM + h * DK + kf * 32 + quad * 8);
    }
  f32x4 of[2][4] = {};
  float mi[2][4], li[2][4];
#pragma unroll
  for (int mt = 0; mt < 2; mt++)
#pragma unroll
    for (int r = 0; r < 4; r++) { mi[mt][r] = -1e30f; li[mt][r] = 0.f; }

  for (int kv0 = 0; kv0 < SKVL; kv0 += 64) {
    __syncthreads();
#pragma unroll
    for (int r = 0; r < 2; r++) {
      gload16(Kb + (size_t)(b * SKVL + kv0 + w * 16 + l15) * DM + h * DK + r * 32 + quad * 8,
              &Kl[(w * 128 + r * 64) * 8]);
      gload16(Vt + (size_t)((b * NH + h) * DK + w * 16 + l15) * SKVL + kv0 + r * 32 + quad * 8,
              &Vl[(w * 128 + r * 64) * 8]);
    }
    __syncthreads();

    short8 kfr[4][2];
#pragma unroll
    for (int nt = 0; nt < 4; nt++)
#pragma unroll
      for (int kf = 0; kf < 2; kf++)
        kfr[nt][kf] = *(const short8*)&Kl[((nt * 128 + kf * 64) + lane) * 8];

    f32x4 s[2][4];
#pragma unroll
    for (int mt = 0; mt < 2; mt++)
#pragma unroll
      for (int nt = 0; nt < 4; nt++) {
        f32x4 t = {0.f, 0.f, 0.f, 0.f};
        t = __builtin_amdgcn_mfma_f32_16x16x32_bf16(qf[mt][0], kfr[nt][0], t, 0, 0, 0);
        t = __builtin_amdgcn_mfma_f32_16x16x32_bf16(qf[mt][1], kfr[nt][1], t, 0, 0, 0);
        s[mt][nt] = t;
      }

    float mv[4];
#pragma unroll
    for (int nt = 0; nt < 4; nt++) mv[nt] = mask[b * SKVL + kv0 + nt * 16 + l15];

#pragma unroll
    for (int mt = 0; mt < 2; mt++)
#pragma unroll
      for (int r = 0; r < 4; r++) {
        float s0 = (s[mt][0][r] + mv[0]) * LOG2E;
        float s1 = (s[mt][1][r] + mv[1]) * LOG2E;
        float s2 = (s[mt][2][r] + mv[2]) * LOG2E;
        float s3 = (s[mt][3][r] + mv[3]) * LOG2E;
        float rm = fmaxf(fmaxf(s0, s1), fmaxf(s2, s3));
#pragma unroll
        for (int msk = 1; msk < 16; msk <<= 1) rm = fmaxf(rm, __shfl_xor(rm, msk, 64));
        float mnew = fmaxf(mi[mt][r], rm);
        float alpha = exp2f(mi[mt][r] - mnew);
        mi[mt][r] = mnew;
        float p0 = exp2f(s0 - mnew), p1 = exp2f(s1 - mnew);
        float p2 = exp2f(s2 - mnew), p3 = exp2f(s3 - mnew);
        float rs = p0 + p1 + p2 + p3;
#pragma unroll
        for (int msk = 1; msk < 16; msk <<= 1) rs += __shfl_xor(rs, msk, 64);
        li[mt][r] = li[mt][r] * alpha + rs;
#pragma unroll
        for (int nt = 0; nt < 4; nt++) of[mt][nt][r] *= alpha;
        s[mt][0][r] = p0; s[mt][1][r] = p1; s[mt][2][r] = p2; s[mt][3][r] = p3;
      }

    // P (C-layout) -> per-wave LDS in A-operand layout, bf16
#pragma unroll
    for (int mt = 0; mt < 2; mt++)
#pragma unroll
      for (int nt = 0; nt < 4; nt++) {
        int kvl = nt * 16 + l15;
        int unit = mt * 128 + (kvl >> 5) * 64 + ((kvl >> 3) & 3) * 16;
#pragma unroll
        for (int r = 0; r < 4; r++)
          Pl[w][(unit + quad * 4 + r) * 8 + (kvl & 7)] = f2bf(s[mt][nt][r]);
      }
    __builtin_amdgcn_s_waitcnt(0);  // drain our ds_writes before reading Pl[w] (wave-private)

    short8 vfr[4][2], pa[2][2];
#pragma unroll
    for (int nt = 0; nt < 4; nt++)
#pragma unroll
      for (int kf = 0; kf < 2; kf++)
        vfr[nt][kf] = *(const short8*)&Vl[((nt * 128 + kf * 64) + lane) * 8];
#pragma unroll
    for (int mt = 0; mt < 2; mt++)
#pragma unroll
      for (int kf = 0; kf < 2; kf++)
        pa[mt][kf] = *(const short8*)&Pl[w][((mt * 128 + kf * 64) + lane) * 8];

#pragma unroll
    for (int mt = 0; mt < 2; mt++)
#pragma unroll
      for (int nt = 0; nt < 4; nt++) {
        of[mt][nt] = __builtin_amdgcn_mfma_f32_16x16x32_bf16(pa[mt][0], vfr[nt][0], of[mt][nt], 0, 0, 0);
        of[mt][nt] = __builtin_amdgcn_mfma_f32_16x16x32_bf16(pa[mt][1], vfr[nt][1], of[mt][nt], 0, 0, 0);
      }
  }

#pragma unroll
  for (int mt = 0; mt < 2; mt++)
#pragma unroll
    for (int nt = 0; nt < 4; nt++) {
      int d = nt * 16 + l15;
#pragma unroll
      for (int r = 0; r < 4; r++) {
        int q = qb * 128 + w * 32 + mt * 16 + quad * 4 + r;
        ctx[(size_t)(b * SQL + q) * DM + h * DK + d] = f2bf(of[mt][nt][r] / li[mt][r]);
      }
    }
}

extern "C" void kernel_launch(void* const* d_in, const int* in_sizes, int n_in,
                              void* d_out, int out_size, void* d_ws, size_t ws_size,
                              hipStream_t stream) {
  const float* hidden = (const float*)d_in[0];
  const float* kvs    = (const float*)d_in[1];
  const float* mask   = (const float*)d_in[2];
  const float* lnw    = (const float*)d_in[3];
  const float* Wq     = (const float*)d_in[4];
  const float* Wk     = (const float*)d_in[5];
  const float* Wv     = (const float*)d_in[6];
  const float* Wo     = (const float*)d_in[7];
  char* ws = (char*)d_ws;

  u16* normed = (u16*)(ws + 0);           // 8 MB
  u16* kvb    = (u16*)(ws + 8388608);     // 16 MB
  u16* Wqt    = (u16*)(ws + 25165824);    // 2 MB
  u16* Wkt    = (u16*)(ws + 27262976);
  u16* Wvt    = (u16*)(ws + 29360128);
  u16* Wot    = (u16*)(ws + 31457280);
  u16* Qb     = (u16*)(ws + 33554432);    // 8 MB
  u16* Kbf    = (u16*)(ws + 41943040);    // 16 MB
  u16* Vtb    = (u16*)(ws + 58720256);    // 16 MB (transposed V)
  u16* ctxb   = (u16*)(ws + 75497472);    // 8 MB  -> total 80 MB

  rmsnorm_kernel<<<BB * SQL, 256, 0, stream>>>(hidden, lnw, normed);
  cvt_kernel<<<(BB * SKVL * DM) / 1024, 256, 0, stream>>>(kvs, kvb);
  dim3 tg(32, 32);
  tcvt_kernel<<<tg, 256, 0, stream>>>(Wq, Wqt);
  tcvt_kernel<<<tg, 256, 0, stream>>>(Wk, Wkt);
  tcvt_kernel<<<tg, 256, 0, stream>>>(Wv, Wvt);
  tcvt_kernel<<<tg, 256, 0, stream>>>(Wo, Wot);

  gemm_kernel<0><<<dim3(32, 8), 256, 0, stream>>>(normed, Wqt, Qb, nullptr, 1024);
  gemm_kernel<0><<<dim3(64, 8), 256, 0, stream>>>(kvb, Wkt, Kbf, nullptr, 1024);
  gemm_kernel<1><<<dim3(64, 8), 256, 0, stream>>>(kvb, Wvt, Vtb, nullptr, 1024);

  flash_kernel<<<dim3(SQL / 128, BB * NH), 256, 0, stream>>>(Qb, Kbf, Vtb, mask, ctxb);

  gemm_kernel<2><<<dim3(32, 8), 256, 0, stream>>>(ctxb, Wot, d_out, hidden, 1024);
}

// Round 2
// 375.840 us; speedup vs baseline: 1.3712x; 1.3712x over previous
//
#include <hip/hip_runtime.h>

typedef unsigned short u16;
typedef unsigned int u32;
typedef __attribute__((ext_vector_type(4))) float f32x4;
typedef __attribute__((ext_vector_type(8))) short short8;

#define BB   2
#define SQL  2048
#define SKVL 4096
#define DM   1024
#define NH   16
#define DK   64
#define L2E  1.44269504f

#if __has_builtin(__builtin_amdgcn_exp2f)
#define EXP2(x) __builtin_amdgcn_exp2f(x)
#else
#define EXP2(x) exp2f(x)
#endif

__device__ __forceinline__ u16 f2bf(float f) {
  union { float f; unsigned u; } v; v.f = f;
  unsigned r = v.u + 0x7fff + ((v.u >> 16) & 1);   // RNE
  return (u16)(r >> 16);
}

// async global->LDS, 16B per lane; lds base wave-uniform, lane i -> base + i*16.
__device__ __forceinline__ void gload16(const void* g, void* lds) {
  __builtin_amdgcn_global_load_lds(
      (const __attribute__((address_space(1))) unsigned int*)g,
      (__attribute__((address_space(3))) unsigned int*)lds, 16, 0, 0);
}

// ---------------- RMSNorm: fp32 in -> bf16 out ----------------
__global__ void rmsnorm_kernel(const float* __restrict__ x, const float* __restrict__ w,
                               u16* __restrict__ out) {
  int row = blockIdx.x;
  int t = threadIdx.x;
  float4 v = ((const float4*)(x + (size_t)row * DM))[t];
  float ss = v.x * v.x + v.y * v.y + v.z * v.z + v.w * v.w;
#pragma unroll
  for (int m = 32; m >= 1; m >>= 1) ss += __shfl_xor(ss, m, 64);
  __shared__ float red[4];
  int lane = t & 63, wv = t >> 6;
  if (lane == 0) red[wv] = ss;
  __syncthreads();
  float total = red[0] + red[1] + red[2] + red[3];
  float scale = rsqrtf(total * (1.0f / DM) + 1e-6f);
  float4 g = ((const float4*)w)[t];
  ushort4 o;
  o.x = f2bf(v.x * scale * g.x);
  o.y = f2bf(v.y * scale * g.y);
  o.z = f2bf(v.z * scale * g.z);
  o.w = f2bf(v.w * scale * g.w);
  ((ushort4*)(out + (size_t)row * DM))[t] = o;
}

// ---------------- fp32 -> bf16 elementwise ----------------
__global__ void cvt_kernel(const float* __restrict__ in, u16* __restrict__ out) {
  int i = blockIdx.x * 256 + threadIdx.x;
  float4 v = ((const float4*)in)[i];
  ushort4 o;
  o.x = f2bf(v.x); o.y = f2bf(v.y); o.z = f2bf(v.z); o.w = f2bf(v.w);
  ((ushort4*)out)[i] = o;
}

// ---------------- W[k][n] fp32 -> Wt[n][k] bf16 ----------------
__global__ void tcvt_kernel(const float* __restrict__ W, u16* __restrict__ Wt) {
  __shared__ float tile[32][33];
  int tx = threadIdx.x & 31, ty = threadIdx.x >> 5;
  int k0 = blockIdx.y * 32, n0 = blockIdx.x * 32;
#pragma unroll
  for (int i = 0; i < 4; i++)
    tile[ty + i * 8][tx] = W[(size_t)(k0 + ty + i * 8) * DM + n0 + tx];
  __syncthreads();
#pragma unroll
  for (int i = 0; i < 4; i++)
    Wt[(size_t)(n0 + ty + i * 8) * DM + k0 + tx] = f2bf(tile[tx][ty + i * 8]);
}

// ---------------- 128x128 GEMM over K=1024 ----------------
// MODE 0: C = bf16 [M][N] of acc*scale (Q path, scale=log2e)
// MODE 2: C = f32 [M][N] of resid + acc (O path)
// MODE 3: merged KV: blockIdx.y<8 -> K bf16 [M][1024]; else V^T bf16 [B][NH][DK][SKV] scaled by exp2(mask*log2e)
template <int MODE>
__global__ void gemm_kernel(const u16* __restrict__ A, const u16* __restrict__ Bt,
                            void* __restrict__ C, void* __restrict__ C2,
                            const float* __restrict__ aux, int N, float scale) {
  const int K = 1024;
  __shared__ __align__(16) u16 Al[128 * 32];
  __shared__ __align__(16) u16 Bl[128 * 32];
  int tid = threadIdx.x, lane = tid & 63, w = tid >> 6;
  int l15 = lane & 15, quad = lane >> 4;
  int wy = w >> 1, wx = w & 1;
  int tm = blockIdx.x * 128, tn = blockIdx.y * 128;
  f32x4 acc[4][4] = {};

  for (int k0 = 0; k0 < K; k0 += 32) {
    __syncthreads();
#pragma unroll
    for (int r = 0; r < 2; r++) {
      int mg = w * 2 + r;
      gload16(A + (size_t)(tm + mg * 16 + l15) * K + k0 + quad * 8, &Al[mg * 512]);
      gload16(Bt + (size_t)(tn + mg * 16 + l15) * K + k0 + quad * 8, &Bl[mg * 512]);
    }
    __syncthreads();
    short8 af[4], bfr[4];
#pragma unroll
    for (int i = 0; i < 4; i++) {
      af[i] = *(const short8*)&Al[((wy * 4 + i) * 64 + lane) * 8];
      bfr[i] = *(const short8*)&Bl[((wx * 4 + i) * 64 + lane) * 8];
    }
#pragma unroll
    for (int mt = 0; mt < 4; mt++)
#pragma unroll
      for (int nt = 0; nt < 4; nt++)
        acc[mt][nt] = __builtin_amdgcn_mfma_f32_16x16x32_bf16(af[mt], bfr[nt], acc[mt][nt], 0, 0, 0);
  }

#pragma unroll
  for (int mt = 0; mt < 4; mt++) {
    int m0 = tm + wy * 64 + mt * 16 + quad * 4;
#pragma unroll
    for (int nt = 0; nt < 4; nt++) {
      int n = tn + wx * 64 + nt * 16 + l15;
      if (MODE == 0) {
#pragma unroll
        for (int r = 0; r < 4; r++)
          ((u16*)C)[(size_t)(m0 + r) * N + n] = f2bf(acc[mt][nt][r] * scale);
      } else if (MODE == 2) {
#pragma unroll
        for (int r = 0; r < 4; r++) {
          size_t idx = (size_t)(m0 + r) * N + n;
          ((float*)C)[idx] = aux[idx] + acc[mt][nt][r];
        }
      } else {  // MODE 3
        if (tn < 1024) {
#pragma unroll
          for (int r = 0; r < 4; r++)
            ((u16*)C)[(size_t)(m0 + r) * 1024 + n] = f2bf(acc[mt][nt][r]);
        } else {
          int nv = n - 1024;
          int h = nv >> 6, d = nv & 63;
          int b = m0 >> 12, skv = m0 & 4095;
          float4 mv = *(const float4*)(aux + (size_t)b * SKVL + skv);
          ushort4 o;
          o.x = f2bf(acc[mt][nt][0] * EXP2(mv.x * L2E));
          o.y = f2bf(acc[mt][nt][1] * EXP2(mv.y * L2E));
          o.z = f2bf(acc[mt][nt][2] * EXP2(mv.z * L2E));
          o.w = f2bf(acc[mt][nt][3] * EXP2(mv.w * L2E));
          *(ushort4*)((u16*)C2 + (size_t)((b * NH + h) * DK + d) * SKVL + skv) = o;
        }
      }
    }
  }
}

#define MFMA(a, b, c) __builtin_amdgcn_mfma_f32_16x16x32_bf16(a, b, c, 0, 0, 0)

// ---------------- flash attention, no-max streaming softmax ----------------
// grid (SQ/128, B*NH), 256 threads = 4 waves, wave owns 32 q rows. KV tile 64.
// Q is pre-scaled by log2e. S^T = K*Q^T so each lane holds 4 consecutive kv.
// l = sum(P * pm) accumulated via MFMA with B-frag = pm (exp2 of mask).
__global__ __launch_bounds__(256, 2) void flash_kernel(
    const u16* __restrict__ Qp, const u16* __restrict__ Kp, const u16* __restrict__ Vtp,
    const float* __restrict__ mask, u16* __restrict__ ctx) {
  __shared__ __align__(16) u16 Kl[64 * 64];      // 8 units [quad][16 kv][8 d]
  __shared__ __align__(16) u16 Vl[64 * 64];      // 8 units [quad][16 d][8 kv]
  __shared__ __align__(16) u16 Pl[4][2048];      // per-wave A-layout [mt][kf][quad][16 q][8 kv]
  __shared__ __align__(16) u16 pml[SKVL];        // bf16 exp2(mask*log2e) for this b

  int tid = threadIdx.x, lane = tid & 63, w = tid >> 6;
  int l15 = lane & 15, quad = lane >> 4;
  int qb = blockIdx.x, bh = blockIdx.y;
  int b = bh >> 4, h = bh & 15;
  int q0 = qb * 128 + w * 32;

  // fill pml (once per block): 256 threads x 16 elems
  {
    int i0 = tid * 16;
#pragma unroll
    for (int g = 0; g < 4; g++) {
      float4 mv = *(const float4*)(mask + (size_t)b * SKVL + i0 + g * 4);
      ushort4 o;
      o.x = f2bf(EXP2(mv.x * L2E)); o.y = f2bf(EXP2(mv.y * L2E));
      o.z = f2bf(EXP2(mv.z * L2E)); o.w = f2bf(EXP2(mv.w * L2E));
      *(ushort4*)&pml[i0 + g * 4] = o;
    }
  }

  // persistent Q B-frags
  short8 qf[2][2];
#pragma unroll
  for (int mt = 0; mt < 2; mt++)
#pragma unroll
    for (int kf = 0; kf < 2; kf++)
      qf[mt][kf] = *(const short8*)(Qp + (size_t)(b * SQL + q0 + mt * 16 + l15) * DM +
                                    h * DK + kf * 32 + quad * 8);

  f32x4 of[2][4] = {};
  f32x4 la[2] = {};
  const int pbase = (quad >> 1) * 256 + (quad & 1) * 8 + l15 * 16;  // byte offset in Pl[w]
  char* plw = (char*)&Pl[w][0];

  for (int kv0 = 0; kv0 < SKVL; kv0 += 64) {
    __syncthreads();
    {  // stage: wave w loads K units 2w,2w+1 and V units 2w,2w+1
#pragma unroll
      for (int r = 0; r < 2; r++) {
        int g = w * 2 + r;
        int kt = g >> 1, kf = g & 1;
        gload16(Kp + (size_t)(b * SKVL + kv0 + kt * 16 + l15) * DM + h * DK + kf * 32 + quad * 8,
                &Kl[g * 512]);
        gload16(Vtp + (size_t)((b * NH + h) * DK + kt * 16 + l15) * SKVL + kv0 + kf * 32 + quad * 8,
                &Vl[g * 512]);
      }
    }
    __syncthreads();

    // S^T = K*Q^T -> exp2 -> pack -> P (A-layout) in wave-private LDS
#pragma unroll
    for (int kt = 0; kt < 4; kt++) {
      short8 k0 = *(const short8*)&Kl[((kt * 2 + 0) * 64 + lane) * 8];
      short8 k1 = *(const short8*)&Kl[((kt * 2 + 1) * 64 + lane) * 8];
#pragma unroll
      for (int mt = 0; mt < 2; mt++) {
        f32x4 st = {0.f, 0.f, 0.f, 0.f};
        st = MFMA(k0, qf[mt][0], st);
        st = MFMA(k1, qf[mt][1], st);
        union { float f; u32 u; } c0, c1, c2, c3;
        c0.f = EXP2(st[0]); c1.f = EXP2(st[1]);
        c2.f = EXP2(st[2]); c3.f = EXP2(st[3]);
        uint2 pk;
        pk.x = ((c0.u + 0x8000u) >> 16) | ((c1.u + 0x8000u) & 0xffff0000u);
        pk.y = ((c2.u + 0x8000u) >> 16) | ((c3.u + 0x8000u) & 0xffff0000u);
        *(uint2*)(plw + mt * 2048 + kt * 512 + pbase) = pk;
      }
    }
    asm volatile("s_waitcnt lgkmcnt(0)" ::: "memory");  // drain own ds_writes (wave-private P)

    // O += P*V', l += P*pm
#pragma unroll
    for (int kf = 0; kf < 2; kf++) {
      short8 pmf = *(const short8*)&pml[kv0 + kf * 32 + quad * 8];
      short8 pa0 = *(const short8*)(plw + ((0 * 2 + kf) * 4 + quad) * 256 + l15 * 16);
      short8 pa1 = *(const short8*)(plw + ((1 * 2 + kf) * 4 + quad) * 256 + l15 * 16);
      la[0] = MFMA(pa0, pmf, la[0]);
      la[1] = MFMA(pa1, pmf, la[1]);
#pragma unroll
      for (int nt = 0; nt < 4; nt++) {
        short8 vf = *(const short8*)&Vl[((nt * 2 + kf) * 64 + lane) * 8];
        of[0][nt] = MFMA(pa0, vf, of[0][nt]);
        of[1][nt] = MFMA(pa1, vf, of[1][nt]);
      }
    }
  }

#pragma unroll
  for (int mt = 0; mt < 2; mt++)
#pragma unroll
    for (int r = 0; r < 4; r++) {
      float inv = 1.0f / la[mt][r];
      int q = q0 + mt * 16 + quad * 4 + r;
#pragma unroll
      for (int nt = 0; nt < 4; nt++) {
        int d = nt * 16 + l15;
        ctx[(size_t)(b * SQL + q) * DM + h * DK + d] = f2bf(of[mt][nt][r] * inv);
      }
    }
}

extern "C" void kernel_launch(void* const* d_in, const int* in_sizes, int n_in,
                              void* d_out, int out_size, void* d_ws, size_t ws_size,
                              hipStream_t stream) {
  const float* hidden = (const float*)d_in[0];
  const float* kvs    = (const float*)d_in[1];
  const float* mask   = (const float*)d_in[2];
  const float* lnw    = (const float*)d_in[3];
  const float* Wq     = (const float*)d_in[4];
  const float* Wk     = (const float*)d_in[5];
  const float* Wv     = (const float*)d_in[6];
  const float* Wo     = (const float*)d_in[7];
  char* ws = (char*)d_ws;

  u16* normed = (u16*)(ws + 0);           // 8 MB
  u16* kvb    = (u16*)(ws + 8388608);     // 16 MB
  u16* Wqt    = (u16*)(ws + 25165824);    // 2 MB
  u16* Wkt    = (u16*)(ws + 27262976);    // 2 MB  (Wkt||Wvt contiguous, 2048 rows)
  u16* Wvt    = (u16*)(ws + 29360128);
  u16* Wot    = (u16*)(ws + 31457280);
  u16* Qb     = (u16*)(ws + 33554432);    // 8 MB  (pre-scaled by log2e)
  u16* Kbf    = (u16*)(ws + 41943040);    // 16 MB
  u16* Vtb    = (u16*)(ws + 58720256);    // 16 MB (V^T * pm)
  u16* ctxb   = (u16*)(ws + 75497472);    // 8 MB

  rmsnorm_kernel<<<BB * SQL, 256, 0, stream>>>(hidden, lnw, normed);
  cvt_kernel<<<(BB * SKVL * DM) / 1024, 256, 0, stream>>>(kvs, kvb);
  dim3 tg(32, 32);
  tcvt_kernel<<<tg, 256, 0, stream>>>(Wq, Wqt);
  tcvt_kernel<<<tg, 256, 0, stream>>>(Wk, Wkt);
  tcvt_kernel<<<tg, 256, 0, stream>>>(Wv, Wvt);
  tcvt_kernel<<<tg, 256, 0, stream>>>(Wo, Wot);

  // Q = normed @ Wq, scaled by log2e
  gemm_kernel<0><<<dim3(32, 8), 256, 0, stream>>>(normed, Wqt, Qb, nullptr, nullptr, 1024, L2E);
  // K | V^T merged (V scaled by exp2(mask*log2e))
  gemm_kernel<3><<<dim3(64, 16), 256, 0, stream>>>(kvb, Wkt, Kbf, Vtb, mask, 2048, 1.0f);

  flash_kernel<<<dim3(SQL / 128, BB * NH), 256, 0, stream>>>(Qb, Kbf, Vtb, mask, ctxb);

  // out = hidden + ctx @ Wo
  gemm_kernel<2><<<dim3(32, 8), 256, 0, stream>>>(ctxb, Wot, d_out, nullptr, hidden, 1024, 1.0f);
}

// Round 3
// 350.857 us; speedup vs baseline: 1.4688x; 1.0712x over previous
//
#include <hip/hip_runtime.h>

typedef unsigned short u16;
typedef unsigned int u32;
typedef __attribute__((ext_vector_type(4))) float f32x4;
typedef __attribute__((ext_vector_type(8))) short short8;

#define BB   2
#define SQL  2048
#define SKVL 4096
#define DM   1024
#define NH   16
#define DK   64
#define L2E  1.44269504f

#if __has_builtin(__builtin_amdgcn_exp2f)
#define EXP2(x) __builtin_amdgcn_exp2f(x)
#else
#define EXP2(x) exp2f(x)
#endif

__device__ __forceinline__ u16 f2bf(float f) {
  union { float f; unsigned u; } v; v.f = f;
  unsigned r = v.u + 0x7fff + ((v.u >> 16) & 1);   // RNE
  return (u16)(r >> 16);
}

// async global->LDS, 16B per lane; lds base wave-uniform, lane i -> base + i*16.
__device__ __forceinline__ void gload16(const void* g, void* lds) {
  __builtin_amdgcn_global_load_lds(
      (const __attribute__((address_space(1))) unsigned int*)g,
      (__attribute__((address_space(3))) unsigned int*)lds, 16, 0, 0);
}

#define MFMA(a, b, c) __builtin_amdgcn_mfma_f32_16x16x32_bf16(a, b, c, 0, 0, 0)

// ---------------- RMSNorm: fp32 in -> bf16 out ----------------
__global__ void rmsnorm_kernel(const float* __restrict__ x, const float* __restrict__ w,
                               u16* __restrict__ out) {
  int row = blockIdx.x;
  int t = threadIdx.x;
  float4 v = ((const float4*)(x + (size_t)row * DM))[t];
  float ss = v.x * v.x + v.y * v.y + v.z * v.z + v.w * v.w;
#pragma unroll
  for (int m = 32; m >= 1; m >>= 1) ss += __shfl_xor(ss, m, 64);
  __shared__ float red[4];
  int lane = t & 63, wv = t >> 6;
  if (lane == 0) red[wv] = ss;
  __syncthreads();
  float total = red[0] + red[1] + red[2] + red[3];
  float scale = rsqrtf(total * (1.0f / DM) + 1e-6f);
  float4 g = ((const float4*)w)[t];
  ushort4 o;
  o.x = f2bf(v.x * scale * g.x);
  o.y = f2bf(v.y * scale * g.y);
  o.z = f2bf(v.z * scale * g.z);
  o.w = f2bf(v.w * scale * g.w);
  ((ushort4*)(out + (size_t)row * DM))[t] = o;
}

// ---------------- fp32 -> bf16 elementwise ----------------
__global__ void cvt_kernel(const float* __restrict__ in, u16* __restrict__ out) {
  int i = blockIdx.x * 256 + threadIdx.x;
  float4 v = ((const float4*)in)[i];
  ushort4 o;
  o.x = f2bf(v.x); o.y = f2bf(v.y); o.z = f2bf(v.z); o.w = f2bf(v.w);
  ((ushort4*)out)[i] = o;
}

// ---------------- 4x W[k][n] fp32 -> Wt[n][k] bf16, one dispatch ----------------
__global__ void tcvt4_kernel(const float* __restrict__ W0, const float* __restrict__ W1,
                             const float* __restrict__ W2, const float* __restrict__ W3,
                             u16* __restrict__ O0, u16* __restrict__ O1,
                             u16* __restrict__ O2, u16* __restrict__ O3) {
  const float* W; u16* Wt;
  switch (blockIdx.z) {
    case 0: W = W0; Wt = O0; break;
    case 1: W = W1; Wt = O1; break;
    case 2: W = W2; Wt = O2; break;
    default: W = W3; Wt = O3; break;
  }
  __shared__ float tile[32][33];
  int tx = threadIdx.x & 31, ty = threadIdx.x >> 5;
  int k0 = blockIdx.y * 32, n0 = blockIdx.x * 32;
#pragma unroll
  for (int i = 0; i < 4; i++)
    tile[ty + i * 8][tx] = W[(size_t)(k0 + ty + i * 8) * DM + n0 + tx];
  __syncthreads();
#pragma unroll
  for (int i = 0; i < 4; i++)
    Wt[(size_t)(n0 + ty + i * 8) * DM + k0 + tx] = f2bf(tile[tx][ty + i * 8]);
}

// ---------------- 128x128 GEMM over K=1024 (Q and O paths) ----------------
// MODE 0: C = bf16 [M][N] of acc*scale.  MODE 2: C = f32 [M][N] of resid + acc.
template <int MODE>
__global__ void gemm_kernel(const u16* __restrict__ A, const u16* __restrict__ Bt,
                            void* __restrict__ C, const float* __restrict__ aux,
                            int N, float scale) {
  const int K = 1024;
  __shared__ __align__(16) u16 Al[128 * 32];
  __shared__ __align__(16) u16 Bl[128 * 32];
  int tid = threadIdx.x, lane = tid & 63, w = tid >> 6;
  int l15 = lane & 15, quad = lane >> 4;
  int wy = w >> 1, wx = w & 1;
  int tm = blockIdx.x * 128, tn = blockIdx.y * 128;
  f32x4 acc[4][4] = {};

  for (int k0 = 0; k0 < K; k0 += 32) {
    __syncthreads();
#pragma unroll
    for (int r = 0; r < 2; r++) {
      int mg = w * 2 + r;
      gload16(A + (size_t)(tm + mg * 16 + l15) * K + k0 + quad * 8, &Al[mg * 512]);
      gload16(Bt + (size_t)(tn + mg * 16 + l15) * K + k0 + quad * 8, &Bl[mg * 512]);
    }
    __syncthreads();
    short8 af[4], bfr[4];
#pragma unroll
    for (int i = 0; i < 4; i++) {
      af[i] = *(const short8*)&Al[((wy * 4 + i) * 64 + lane) * 8];
      bfr[i] = *(const short8*)&Bl[((wx * 4 + i) * 64 + lane) * 8];
    }
#pragma unroll
    for (int mt = 0; mt < 4; mt++)
#pragma unroll
      for (int nt = 0; nt < 4; nt++)
        acc[mt][nt] = MFMA(af[mt], bfr[nt], acc[mt][nt]);
  }

#pragma unroll
  for (int mt = 0; mt < 4; mt++) {
    int m0 = tm + wy * 64 + mt * 16 + quad * 4;
#pragma unroll
    for (int nt = 0; nt < 4; nt++) {
      int n = tn + wx * 64 + nt * 16 + l15;
      if (MODE == 0) {
#pragma unroll
        for (int r = 0; r < 4; r++)
          ((u16*)C)[(size_t)(m0 + r) * N + n] = f2bf(acc[mt][nt][r] * scale);
      } else {
#pragma unroll
        for (int r = 0; r < 4; r++) {
          size_t idx = (size_t)(m0 + r) * N + n;
          ((float*)C)[idx] = aux[idx] + acc[mt][nt][r];
        }
      }
    }
  }
}

// ---------------- merged K / V^T GEMM, 1024 blocks ----------------
// bid<512: K = X@Wk, bf16 [8192][1024] row-major tokens.
// bid>=512: V^T = (X@Wv)^T computed directly as Wv^T @ X^T: M=inner, N=tokens,
//           stores coalesced along skv, scaled by exp2(mask*log2e).
__global__ void kvgemm_kernel(const u16* __restrict__ kvb, const u16* __restrict__ Wkt,
                              const u16* __restrict__ Wvt, u16* __restrict__ Kbf,
                              u16* __restrict__ Vtb, const float* __restrict__ mask) {
  const int K = 1024;
  __shared__ __align__(16) u16 Al[128 * 32];
  __shared__ __align__(16) u16 Bl[128 * 32];
  int tid = threadIdx.x, lane = tid & 63, w = tid >> 6;
  int l15 = lane & 15, quad = lane >> 4;
  int wy = w >> 1, wx = w & 1;

  int bid = blockIdx.x;
  bool vmode = bid >= 512;
  const u16 *A, *Bt;
  int tm, tn;
  if (!vmode) { A = kvb; Bt = Wkt; tm = (bid & 63) * 128; tn = (bid >> 6) * 128; }
  else { int vid = bid - 512; A = Wvt; Bt = kvb; tm = (vid & 7) * 128; tn = (vid >> 3) * 128; }

  f32x4 acc[4][4] = {};
  for (int k0 = 0; k0 < K; k0 += 32) {
    __syncthreads();
#pragma unroll
    for (int r = 0; r < 2; r++) {
      int mg = w * 2 + r;
      gload16(A + (size_t)(tm + mg * 16 + l15) * K + k0 + quad * 8, &Al[mg * 512]);
      gload16(Bt + (size_t)(tn + mg * 16 + l15) * K + k0 + quad * 8, &Bl[mg * 512]);
    }
    __syncthreads();
    short8 af[4], bfr[4];
#pragma unroll
    for (int i = 0; i < 4; i++) {
      af[i] = *(const short8*)&Al[((wy * 4 + i) * 64 + lane) * 8];
      bfr[i] = *(const short8*)&Bl[((wx * 4 + i) * 64 + lane) * 8];
    }
#pragma unroll
    for (int mt = 0; mt < 4; mt++)
#pragma unroll
      for (int nt = 0; nt < 4; nt++)
        acc[mt][nt] = MFMA(af[mt], bfr[nt], acc[mt][nt]);
  }

#pragma unroll
  for (int mt = 0; mt < 4; mt++) {
    int m0 = tm + wy * 64 + mt * 16 + quad * 4;
#pragma unroll
    for (int nt = 0; nt < 4; nt++) {
      int n = tn + wx * 64 + nt * 16 + l15;
      if (!vmode) {
#pragma unroll
        for (int r = 0; r < 4; r++)
          Kbf[(size_t)(m0 + r) * 1024 + n] = f2bf(acc[mt][nt][r]);
      } else {
        // m0 = inner index, n = flat token index (b*4096+skv); mask flat = [b][skv]
        float pm = EXP2(mask[n] * L2E);
        int b = n >> 12, skv = n & 4095;
#pragma unroll
        for (int r = 0; r < 4; r++)
          Vtb[((size_t)(b * 1024 + m0 + r) << 12) + skv] = f2bf(acc[mt][nt][r] * pm);
      }
    }
  }
}

// ---------------- flash attention: mt=4/wave, intra-block kv split ----------------
// grid (16, 32), 256 threads = 4 waves. Waves {0,1}=group0, {2,3}=group1.
// Wave w covers q rows (w&1)*64..+64 (mt=4); group g processes kv tiles i*128+g*64.
// Streaming (no-max) softmax: partials are additive; groups merge via LDS at end.
__global__ __launch_bounds__(256, 2) void flash_kernel(
    const u16* __restrict__ Qp, const u16* __restrict__ Kp, const u16* __restrict__ Vtp,
    const float* __restrict__ mask, u16* __restrict__ ctx) {
  // LDS: [0,16K) Kl2[2][4096]u16 | [16K,32K) Vl2[2][4096]u16 | [32K,64K) Pl[4][8KB]
  //      [64K,72K) pml[4096]u16.  Merge phase reuses [0,32K) as Ox f32[128][64],
  //      [32K,+512) as Ll f32[128].
  __shared__ __align__(16) char smem[73728];
  u16* Kl2 = (u16*)smem;
  u16* Vl2 = (u16*)(smem + 16384);
  char* pl_base = smem + 32768;
  u16* pml = (u16*)(smem + 65536);
  float* Ox = (float*)smem;
  float* Ll = (float*)(smem + 32768);

  int tid = threadIdx.x, lane = tid & 63, w = tid >> 6;
  int l15 = lane & 15, quad = lane >> 4;
  int grp = w >> 1, wg = w & 1;
  int qb = blockIdx.x, bh = blockIdx.y;
  int b = bh >> 4, h = bh & 15;
  int q0 = qb * 128 + wg * 64;

  // pml = bf16 exp2(mask*log2e), whole row for this b
  {
    int i0 = tid * 16;
#pragma unroll
    for (int g = 0; g < 4; g++) {
      float4 mv = *(const float4*)(mask + (size_t)b * SKVL + i0 + g * 4);
      ushort4 o;
      o.x = f2bf(EXP2(mv.x * L2E)); o.y = f2bf(EXP2(mv.y * L2E));
      o.z = f2bf(EXP2(mv.z * L2E)); o.w = f2bf(EXP2(mv.w * L2E));
      *(ushort4*)&pml[i0 + g * 4] = o;
    }
  }

  short8 qf[4][2];
#pragma unroll
  for (int mt = 0; mt < 4; mt++)
#pragma unroll
    for (int kf = 0; kf < 2; kf++)
      qf[mt][kf] = *(const short8*)(Qp + (size_t)(b * SQL + q0 + mt * 16 + l15) * DM +
                                    h * DK + kf * 32 + quad * 8);

  f32x4 of[4][4] = {};
  f32x4 la[4] = {};
  char* plw = pl_base + w * 8192;
  const int pbase = (quad >> 1) * 256 + (quad & 1) * 8 + l15 * 16;
  u16* Klg = Kl2 + grp * 4096;
  u16* Vlg = Vl2 + grp * 4096;

  for (int it = 0; it < 32; ++it) {
    int kv0 = it * 128 + grp * 64;
    __syncthreads();
#pragma unroll
    for (int r = 0; r < 4; r++) {
      int u = wg * 4 + r;
      int kt = u >> 1, kf = u & 1;
      gload16(Kp + (size_t)(b * SKVL + kv0 + kt * 16 + l15) * DM + h * DK + kf * 32 + quad * 8,
              &Klg[u * 512]);
      gload16(Vtp + (size_t)((b * NH + h) * DK + kt * 16 + l15) * SKVL + kv0 + kf * 32 + quad * 8,
              &Vlg[u * 512]);
    }
    __syncthreads();

    // S^T = K*Q^T -> exp2 -> pack -> P (A-layout) in wave-private LDS
#pragma unroll
    for (int kt = 0; kt < 4; kt++) {
      short8 k0 = *(const short8*)&Klg[((kt * 2 + 0) * 64 + lane) * 8];
      short8 k1 = *(const short8*)&Klg[((kt * 2 + 1) * 64 + lane) * 8];
#pragma unroll
      for (int mt = 0; mt < 4; mt++) {
        f32x4 st = {0.f, 0.f, 0.f, 0.f};
        st = MFMA(k0, qf[mt][0], st);
        st = MFMA(k1, qf[mt][1], st);
        union { float f; u32 u; } c0, c1, c2, c3;
        c0.f = EXP2(st[0]); c1.f = EXP2(st[1]);
        c2.f = EXP2(st[2]); c3.f = EXP2(st[3]);
        uint2 pk;
        pk.x = ((c0.u + 0x8000u) >> 16) | ((c1.u + 0x8000u) & 0xffff0000u);
        pk.y = ((c2.u + 0x8000u) >> 16) | ((c3.u + 0x8000u) & 0xffff0000u);
        *(uint2*)(plw + mt * 2048 + kt * 512 + pbase) = pk;
      }
    }
    asm volatile("s_waitcnt lgkmcnt(0)" ::: "memory");  // drain own ds_writes (wave-private P)

    // O += P*V', l += P*pm
#pragma unroll
    for (int kf = 0; kf < 2; kf++) {
      short8 pmf = *(const short8*)&pml[kv0 + kf * 32 + quad * 8];
      short8 pa[4];
#pragma unroll
      for (int mt = 0; mt < 4; mt++)
        pa[mt] = *(const short8*)(plw + ((mt * 2 + kf) * 4 + quad) * 256 + l15 * 16);
#pragma unroll
      for (int mt = 0; mt < 4; mt++) la[mt] = MFMA(pa[mt], pmf, la[mt]);
#pragma unroll
      for (int nt = 0; nt < 4; nt++) {
        short8 vf = *(const short8*)&Vlg[((nt * 2 + kf) * 64 + lane) * 8];
#pragma unroll
        for (int mt = 0; mt < 4; mt++)
          of[mt][nt] = MFMA(pa[mt], vf, of[mt][nt]);
      }
    }
  }

  // merge group partials (additive) via LDS
  __syncthreads();
  if (grp == 1) {
#pragma unroll
    for (int mt = 0; mt < 4; mt++) {
#pragma unroll
      for (int nt = 0; nt < 4; nt++)
#pragma unroll
        for (int r = 0; r < 4; r++)
          Ox[(wg * 64 + mt * 16 + quad * 4 + r) * 64 + nt * 16 + l15] = of[mt][nt][r];
      if (l15 == 0)
#pragma unroll
        for (int r = 0; r < 4; r++) Ll[wg * 64 + mt * 16 + quad * 4 + r] = la[mt][r];
    }
  }
  __syncthreads();
  if (grp == 0) {
#pragma unroll
    for (int mt = 0; mt < 4; mt++)
#pragma unroll
      for (int r = 0; r < 4; r++) {
        int ql = wg * 64 + mt * 16 + quad * 4 + r;
        float inv = 1.0f / (la[mt][r] + Ll[ql]);
        int q = qb * 128 + ql;
#pragma unroll
        for (int nt = 0; nt < 4; nt++) {
          float ov = of[mt][nt][r] + Ox[ql * 64 + nt * 16 + l15];
          ctx[(size_t)(b * SQL + q) * DM + h * DK + nt * 16 + l15] = f2bf(ov * inv);
        }
      }
  }
}

extern "C" void kernel_launch(void* const* d_in, const int* in_sizes, int n_in,
                              void* d_out, int out_size, void* d_ws, size_t ws_size,
                              hipStream_t stream) {
  const float* hidden = (const float*)d_in[0];
  const float* kvs    = (const float*)d_in[1];
  const float* mask   = (const float*)d_in[2];
  const float* lnw    = (const float*)d_in[3];
  const float* Wq     = (const float*)d_in[4];
  const float* Wk     = (const float*)d_in[5];
  const float* Wv     = (const float*)d_in[6];
  const float* Wo     = (const float*)d_in[7];
  char* ws = (char*)d_ws;

  u16* normed = (u16*)(ws + 0);           // 8 MB
  u16* kvb    = (u16*)(ws + 8388608);     // 16 MB
  u16* Wqt    = (u16*)(ws + 25165824);    // 2 MB
  u16* Wkt    = (u16*)(ws + 27262976);    // 2 MB
  u16* Wvt    = (u16*)(ws + 29360128);    // 2 MB
  u16* Wot    = (u16*)(ws + 31457280);    // 2 MB
  u16* Qb     = (u16*)(ws + 33554432);    // 8 MB (pre-scaled by log2e)
  u16* Kbf    = (u16*)(ws + 41943040);    // 16 MB
  u16* Vtb    = (u16*)(ws + 58720256);    // 16 MB (V^T * pm, [b*1024+inner][skv])
  u16* ctxb   = (u16*)(ws + 75497472);    // 8 MB

  rmsnorm_kernel<<<BB * SQL, 256, 0, stream>>>(hidden, lnw, normed);
  cvt_kernel<<<(BB * SKVL * DM) / 1024, 256, 0, stream>>>(kvs, kvb);
  tcvt4_kernel<<<dim3(32, 32, 4), 256, 0, stream>>>(Wq, Wk, Wv, Wo, Wqt, Wkt, Wvt, Wot);

  // Q = normed @ Wq, scaled by log2e
  gemm_kernel<0><<<dim3(32, 8), 256, 0, stream>>>(normed, Wqt, Qb, nullptr, 1024, L2E);
  // K (row-major) and V^T (direct, pm-scaled), one dispatch
  kvgemm_kernel<<<1024, 256, 0, stream>>>(kvb, Wkt, Wvt, Kbf, Vtb, mask);

  flash_kernel<<<dim3(SQL / 128, BB * NH), 256, 0, stream>>>(Qb, Kbf, Vtb, mask, ctxb);

  // out = hidden + ctx @ Wo
  gemm_kernel<2><<<dim3(32, 8), 256, 0, stream>>>(ctxb, Wot, d_out, hidden, 1024, 1.0f);
}

// Round 5
// 329.969 us; speedup vs baseline: 1.5618x; 1.0633x over previous
//
#include <hip/hip_runtime.h>

typedef unsigned short u16;
typedef unsigned int u32;
typedef __attribute__((ext_vector_type(4))) float f32x4;
typedef __attribute__((ext_vector_type(8))) short short8;
typedef __attribute__((ext_vector_type(4))) short short4v;

#define BB   2
#define SQL  2048
#define SKVL 4096
#define DM   1024
#define NH   16
#define DK   64
#define L2E  1.44269504f

#if __has_builtin(__builtin_amdgcn_exp2f)
#define EXP2(x) __builtin_amdgcn_exp2f(x)
#else
#define EXP2(x) exp2f(x)
#endif

#define MFMA32(a, b, c) __builtin_amdgcn_mfma_f32_16x16x32_bf16(a, b, c, 0, 0, 0)
#define MFMA16(a, b, c) __builtin_amdgcn_mfma_f32_16x16x16bf16_1k(a, b, c, 0, 0, 0)

__device__ __forceinline__ u16 f2bf(float f) {
  union { float f; unsigned u; } v; v.f = f;
  unsigned r = v.u + 0x7fff + ((v.u >> 16) & 1);   // RNE
  return (u16)(r >> 16);
}

__device__ __forceinline__ short4v pack4(float p0, float p1, float p2, float p3) {
  union { float f; u32 u; } a, b, c, d;
  a.f = p0; b.f = p1; c.f = p2; d.f = p3;
  union { uint2 v; short4v s; } r;
  r.v.x = ((a.u + 0x8000u) >> 16) | ((b.u + 0x8000u) & 0xffff0000u);
  r.v.y = ((c.u + 0x8000u) >> 16) | ((d.u + 0x8000u) & 0xffff0000u);
  return r.s;
}

// async global->LDS, 16B per lane; lds base wave-uniform, lane i -> base + i*16.
__device__ __forceinline__ void gload16(const void* g, void* lds) {
  __builtin_amdgcn_global_load_lds(
      (const __attribute__((address_space(1))) unsigned int*)g,
      (__attribute__((address_space(3))) unsigned int*)lds, 16, 0, 0);
}

// ---------------- fused preprocessing: rmsnorm | fp32->bf16 cvt | 4x weight transpose ----------------
__global__ void pre_kernel(const float* __restrict__ hidden, const float* __restrict__ lnw,
                           const float* __restrict__ kvs,
                           const float* __restrict__ Wq, const float* __restrict__ Wk,
                           const float* __restrict__ Wv, const float* __restrict__ Wo,
                           u16* __restrict__ normed, u16* __restrict__ kvb,
                           u16* __restrict__ Wqt, u16* __restrict__ Wkt,
                           u16* __restrict__ Wvt, u16* __restrict__ Wot) {
  __shared__ float red[4];
  __shared__ float tile[32][33];
  int bid = blockIdx.x, t = threadIdx.x;
  if (bid < 4096) {
    // RMSNorm of hidden row bid
    int row = bid;
    float4 v = ((const float4*)(hidden + (size_t)row * DM))[t];
    float ss = v.x * v.x + v.y * v.y + v.z * v.z + v.w * v.w;
#pragma unroll
    for (int m = 32; m >= 1; m >>= 1) ss += __shfl_xor(ss, m, 64);
    int lane = t & 63, wv = t >> 6;
    if (lane == 0) red[wv] = ss;
    __syncthreads();
    float total = red[0] + red[1] + red[2] + red[3];
    float scale = rsqrtf(total * (1.0f / DM) + 1e-6f);
    float4 g = ((const float4*)lnw)[t];
    ushort4 o;
    o.x = f2bf(v.x * scale * g.x);
    o.y = f2bf(v.y * scale * g.y);
    o.z = f2bf(v.z * scale * g.z);
    o.w = f2bf(v.w * scale * g.w);
    ((ushort4*)(normed + (size_t)row * DM))[t] = o;
  } else if (bid < 12288) {
    int i = (bid - 4096) * 256 + t;
    float4 v = ((const float4*)kvs)[i];
    ushort4 o;
    o.x = f2bf(v.x); o.y = f2bf(v.y); o.z = f2bf(v.z); o.w = f2bf(v.w);
    ((ushort4*)kvb)[i] = o;
  } else {
    int g = bid - 12288;
    int z = g >> 10;
    const float* W = (z == 0) ? Wq : (z == 1) ? Wk : (z == 2) ? Wv : Wo;
    u16* Wt = (z == 0) ? Wqt : (z == 1) ? Wkt : (z == 2) ? Wvt : Wot;
    int xx = g & 31, yy = (g >> 5) & 31;
    int tx = t & 31, ty = t >> 5;
    int k0 = yy * 32, n0 = xx * 32;
#pragma unroll
    for (int i = 0; i < 4; i++)
      tile[ty + i * 8][tx] = W[(size_t)(k0 + ty + i * 8) * DM + n0 + tx];
    __syncthreads();
#pragma unroll
    for (int i = 0; i < 4; i++)
      Wt[(size_t)(n0 + ty + i * 8) * DM + k0 + tx] = f2bf(tile[tx][ty + i * 8]);
  }
}

// ---------------- merged Q/K/V projection, 1280 blocks ----------------
// bid<256:   Q = normed @ Wq * log2e, bf16 [4096][1024]
// 256..767:  K = kvb @ Wk, bf16 [8192][1024]
// 768..1279: V^T = Wv^T @ kvb^T into flash-friendly blob layout:
//   blob (b,h,kvt of 64 kv) = 4096 u16; chunk o=(p*4+quad)*64+d holds 8 bf16:
//   e -> kv_local = p*32 + (e>>2)*16 + quad*4 + (e&3), value V[kv][d].
__global__ void proj_kernel(const u16* __restrict__ normed, const u16* __restrict__ kvb,
                            const u16* __restrict__ Wqt, const u16* __restrict__ Wkt,
                            const u16* __restrict__ Wvt,
                            u16* __restrict__ Qb, u16* __restrict__ Kbf,
                            u16* __restrict__ Vtb) {
  const int K = 1024;
  __shared__ __align__(16) u16 Al[128 * 32];
  __shared__ __align__(16) u16 Bl[128 * 32];
  int tid = threadIdx.x, lane = tid & 63, w = tid >> 6;
  int l15 = lane & 15, quad = lane >> 4;
  int wy = w >> 1, wx = w & 1;

  int bid = blockIdx.x;
  int mode;
  const u16 *A, *Bt;
  int tm, tn;
  if (bid < 256) { mode = 0; A = normed; Bt = Wqt; tm = (bid & 31) * 128; tn = (bid >> 5) * 128; }
  else if (bid < 768) { mode = 1; A = kvb; Bt = Wkt; int kid = bid - 256; tm = (kid & 63) * 128; tn = (kid >> 6) * 128; }
  else { mode = 2; A = Wvt; Bt = kvb; int vid = bid - 768; tm = (vid & 7) * 128; tn = (vid >> 3) * 128; }

  f32x4 acc[4][4] = {};
  for (int k0 = 0; k0 < K; k0 += 32) {
    __syncthreads();
#pragma unroll
    for (int r = 0; r < 2; r++) {
      int mg = w * 2 + r;
      gload16(A + (size_t)(tm + mg * 16 + l15) * K + k0 + quad * 8, &Al[mg * 512]);
      gload16(Bt + (size_t)(tn + mg * 16 + l15) * K + k0 + quad * 8, &Bl[mg * 512]);
    }
    __syncthreads();
    short8 af[4], bfr[4];
#pragma unroll
    for (int i = 0; i < 4; i++) {
      af[i] = *(const short8*)&Al[((wy * 4 + i) * 64 + lane) * 8];
      bfr[i] = *(const short8*)&Bl[((wx * 4 + i) * 64 + lane) * 8];
    }
#pragma unroll
    for (int mt = 0; mt < 4; mt++)
#pragma unroll
      for (int nt = 0; nt < 4; nt++)
        acc[mt][nt] = MFMA32(af[mt], bfr[nt], acc[mt][nt]);
  }

#pragma unroll
  for (int mt = 0; mt < 4; mt++) {
    int m0 = tm + wy * 64 + mt * 16 + quad * 4;
#pragma unroll
    for (int nt = 0; nt < 4; nt++) {
      int n = tn + wx * 64 + nt * 16 + l15;
      if (mode == 0) {
#pragma unroll
        for (int r = 0; r < 4; r++)
          Qb[(size_t)(m0 + r) * 1024 + n] = f2bf(acc[mt][nt][r] * L2E);
      } else if (mode == 1) {
#pragma unroll
        for (int r = 0; r < 4; r++)
          Kbf[(size_t)(m0 + r) * 1024 + n] = f2bf(acc[mt][nt][r]);
      } else {
        // m0 = inner index (h*64+d), n = token index
        int b = n >> 12, skv = n & 4095;
        int kvt = skv >> 6, kvl = skv & 63;
        int p = kvl >> 5, kth = (kvl >> 4) & 1, qd = (kvl >> 2) & 3, elo = kvl & 3;
        int e = kth * 4 + elo;
        int h = m0 >> 6, d0 = m0 & 63;
        size_t base = ((size_t)((b * NH + h) * 64 + kvt) << 12) + (size_t)(p * 4 + qd) * 512 + e;
#pragma unroll
        for (int r = 0; r < 4; r++)
          Vtb[base + (size_t)(d0 + r) * 8] = f2bf(acc[mt][nt][r]);
      }
    }
  }
}

// ---------------- flash attention: reg-resident P (16x16x16 PV), dbuf K/V ----------------
// grid (16, 32), 4 waves: wg=w&1 picks q half (64 rows), grp=w>>1 picks kv parity.
// Streaming no-max softmax; l via per-lane rowsum + end shuffle-reduce.
__global__ __launch_bounds__(256, 2) void flash_kernel(
    const u16* __restrict__ Qp, const u16* __restrict__ Kp, const u16* __restrict__ Vtb,
    const float* __restrict__ mask, u16* __restrict__ ctx) {
  __shared__ __align__(16) char smem[81920];
  u16* Kbuf = (u16*)smem;                 // [buf2][grp2][4096]
  u16* Vbuf = (u16*)(smem + 32768);       // [buf2][grp2][4096]
  float* mlog = (float*)(smem + 65536);   // [4096] mask*log2e
  float* Ox = (float*)smem;               // merge reuse: [128][64]
  float* Ll = (float*)(smem + 32768);     // merge reuse: [128]

  int tid = threadIdx.x, lane = tid & 63, w = tid >> 6;
  int l15 = lane & 15, quad = lane >> 4;
  int grp = w >> 1, wg = w & 1;
  int qb = blockIdx.x, bh = blockIdx.y;
  int b = bh >> 4, h = bh & 15;
  int q0 = qb * 128 + wg * 64;

  // mlog fill: 4096 f32, 16 per thread
  {
    const float* mrow = mask + (size_t)b * SKVL + tid * 16;
#pragma unroll
    for (int g = 0; g < 4; g++) {
      float4 mv = *(const float4*)(mrow + g * 4);
      float4 o; o.x = mv.x * L2E; o.y = mv.y * L2E; o.z = mv.z * L2E; o.w = mv.w * L2E;
      *(float4*)&mlog[tid * 16 + g * 4] = o;
    }
  }

  short8 qf[4][2];
#pragma unroll
  for (int mt = 0; mt < 4; mt++)
#pragma unroll
    for (int kf = 0; kf < 2; kf++)
      qf[mt][kf] = *(const short8*)(Qp + (size_t)(b * SQL + q0 + mt * 16 + l15) * DM +
                                    h * DK + kf * 32 + quad * 8);

  f32x4 of[4][4] = {};
  float ls[4] = {0.f, 0.f, 0.f, 0.f};

  const size_t vblob = (size_t)(b * NH + h) * 64 * 4096;

  auto stage = [&](int tileIdx, int buf) {
    int kv0 = tileIdx * 64;
    u16* Kd = Kbuf + (buf * 2 + grp) * 4096;
    u16* Vd = Vbuf + (buf * 2 + grp) * 4096;
#pragma unroll
    for (int r = 0; r < 4; r++) {
      int u = wg * 4 + r;
      int kt = u >> 1, kf = u & 1;
      gload16(Kp + (size_t)(b * SKVL + kv0 + kt * 16 + l15) * DM + h * DK + kf * 32 + quad * 8,
              &Kd[u * 512]);
      gload16(Vtb + vblob + (size_t)tileIdx * 4096 + u * 512 + lane * 8, &Vd[u * 512]);
    }
  };

  stage(grp, 0);
  for (int it = 0; it < 32; ++it) {
    __syncthreads();                      // tile it landed (loads issued last iter)
    if (it + 1 < 32) stage((it + 1) * 2 + grp, (it + 1) & 1);
    int tileIdx = it * 2 + grp;
    int kv0 = tileIdx * 64;
    const u16* Kg = Kbuf + ((it & 1) * 2 + grp) * 4096;
    const u16* Vg = Vbuf + ((it & 1) * 2 + grp) * 4096;

#pragma unroll
    for (int ktp = 0; ktp < 2; ktp++) {
      short4v pa[2][4];
#pragma unroll
      for (int kth = 0; kth < 2; kth++) {
        int kt = ktp * 2 + kth;
        short8 k0 = *(const short8*)&Kg[((kt * 2 + 0) * 64 + lane) * 8];
        short8 k1 = *(const short8*)&Kg[((kt * 2 + 1) * 64 + lane) * 8];
        f32x4 ml = *(const f32x4*)&mlog[kv0 + kt * 16 + quad * 4];
#pragma unroll
        for (int mt = 0; mt < 4; mt++) {
          f32x4 st = {0.f, 0.f, 0.f, 0.f};
          st = MFMA32(k0, qf[mt][0], st);
          st = MFMA32(k1, qf[mt][1], st);
          float p0 = EXP2(st[0] + ml[0]);
          float p1 = EXP2(st[1] + ml[1]);
          float p2 = EXP2(st[2] + ml[2]);
          float p3 = EXP2(st[3] + ml[3]);
          ls[mt] += (p0 + p1) + (p2 + p3);
          pa[kth][mt] = pack4(p0, p1, p2, p3);
        }
      }
#pragma unroll
      for (int nt = 0; nt < 4; nt++) {
        short8 vv = *(const short8*)&Vg[((ktp * 4 + quad) * 64 + nt * 16 + l15) * 8];
        short4v vlo = {vv[0], vv[1], vv[2], vv[3]};
        short4v vhi = {vv[4], vv[5], vv[6], vv[7]};
#pragma unroll
        for (int mt = 0; mt < 4; mt++) {
          of[mt][nt] = MFMA16(pa[0][mt], vlo, of[mt][nt]);
          of[mt][nt] = MFMA16(pa[1][mt], vhi, of[mt][nt]);
        }
      }
    }
  }

  // reduce rowsums over quads: every lane ends with l for q=its l15 (tile mt)
#pragma unroll
  for (int mt = 0; mt < 4; mt++) {
    ls[mt] += __shfl_xor(ls[mt], 16, 64);
    ls[mt] += __shfl_xor(ls[mt], 32, 64);
  }

  __syncthreads();
  if (grp == 1) {
#pragma unroll
    for (int mt = 0; mt < 4; mt++) {
#pragma unroll
      for (int nt = 0; nt < 4; nt++)
#pragma unroll
        for (int r = 0; r < 4; r++)
          Ox[(wg * 64 + mt * 16 + quad * 4 + r) * 64 + nt * 16 + l15] = of[mt][nt][r];
      if (quad == 0) Ll[wg * 64 + mt * 16 + l15] = ls[mt];
    }
  }
  __syncthreads();
  if (grp == 0) {
#pragma unroll
    for (int mt = 0; mt < 4; mt++) {
      float lt = ls[mt] + Ll[wg * 64 + mt * 16 + l15];   // total l for q=l15
#pragma unroll
      for (int r = 0; r < 4; r++) {
        float lqr = __shfl(lt, quad * 4 + r, 64);        // l for q=quad*4+r
        float inv = 1.0f / lqr;
        int ql = wg * 64 + mt * 16 + quad * 4 + r;
        int q = qb * 128 + ql;
#pragma unroll
        for (int nt = 0; nt < 4; nt++) {
          float ov = of[mt][nt][r] + Ox[ql * 64 + nt * 16 + l15];
          ctx[(size_t)(b * SQL + q) * DM + h * DK + nt * 16 + l15] = f2bf(ov * inv);
        }
      }
    }
  }
}

// ---------------- O projection + residual ----------------
__global__ void ogemm_kernel(const u16* __restrict__ A, const u16* __restrict__ Bt,
                             float* __restrict__ C, const float* __restrict__ resid) {
  const int K = 1024;
  __shared__ __align__(16) u16 Al[128 * 32];
  __shared__ __align__(16) u16 Bl[128 * 32];
  int tid = threadIdx.x, lane = tid & 63, w = tid >> 6;
  int l15 = lane & 15, quad = lane >> 4;
  int wy = w >> 1, wx = w & 1;
  int tm = blockIdx.x * 128, tn = blockIdx.y * 128;
  f32x4 acc[4][4] = {};

  for (int k0 = 0; k0 < K; k0 += 32) {
    __syncthreads();
#pragma unroll
    for (int r = 0; r < 2; r++) {
      int mg = w * 2 + r;
      gload16(A + (size_t)(tm + mg * 16 + l15) * K + k0 + quad * 8, &Al[mg * 512]);
      gload16(Bt + (size_t)(tn + mg * 16 + l15) * K + k0 + quad * 8, &Bl[mg * 512]);
    }
    __syncthreads();
    short8 af[4], bfr[4];
#pragma unroll
    for (int i = 0; i < 4; i++) {
      af[i] = *(const short8*)&Al[((wy * 4 + i) * 64 + lane) * 8];
      bfr[i] = *(const short8*)&Bl[((wx * 4 + i) * 64 + lane) * 8];
    }
#pragma unroll
    for (int mt = 0; mt < 4; mt++)
#pragma unroll
      for (int nt = 0; nt < 4; nt++)
        acc[mt][nt] = MFMA32(af[mt], bfr[nt], acc[mt][nt]);
  }

#pragma unroll
  for (int mt = 0; mt < 4; mt++) {
    int m0 = tm + wy * 64 + mt * 16 + quad * 4;
#pragma unroll
    for (int nt = 0; nt < 4; nt++) {
      int n = tn + wx * 64 + nt * 16 + l15;
#pragma unroll
      for (int r = 0; r < 4; r++) {
        size_t idx = (size_t)(m0 + r) * 1024 + n;
        C[idx] = resid[idx] + acc[mt][nt][r];
      }
    }
  }
}

extern "C" void kernel_launch(void* const* d_in, const int* in_sizes, int n_in,
                              void* d_out, int out_size, void* d_ws, size_t ws_size,
                              hipStream_t stream) {
  const float* hidden = (const float*)d_in[0];
  const float* kvs    = (const float*)d_in[1];
  const float* mask   = (const float*)d_in[2];
  const float* lnw    = (const float*)d_in[3];
  const float* Wq     = (const float*)d_in[4];
  const float* Wk     = (const float*)d_in[5];
  const float* Wv     = (const float*)d_in[6];
  const float* Wo     = (const float*)d_in[7];
  char* ws = (char*)d_ws;

  u16* normed = (u16*)(ws + 0);           // 8 MB
  u16* kvb    = (u16*)(ws + 8388608);     // 16 MB
  u16* Wqt    = (u16*)(ws + 25165824);    // 2 MB
  u16* Wkt    = (u16*)(ws + 27262976);    // 2 MB
  u16* Wvt    = (u16*)(ws + 29360128);    // 2 MB
  u16* Wot    = (u16*)(ws + 31457280);    // 2 MB
  u16* Qb     = (u16*)(ws + 33554432);    // 8 MB (pre-scaled by log2e)
  u16* Kbf    = (u16*)(ws + 41943040);    // 16 MB
  u16* Vtb    = (u16*)(ws + 58720256);    // 16 MB (blob layout)
  u16* ctxb   = (u16*)(ws + 75497472);    // 8 MB

  pre_kernel<<<16384, 256, 0, stream>>>(hidden, lnw, kvs, Wq, Wk, Wv, Wo,
                                        normed, kvb, Wqt, Wkt, Wvt, Wot);
  proj_kernel<<<1280, 256, 0, stream>>>(normed, kvb, Wqt, Wkt, Wvt, Qb, Kbf, Vtb);
  flash_kernel<<<dim3(SQL / 128, BB * NH), 256, 0, stream>>>(Qb, Kbf, Vtb, mask, ctxb);
  ogemm_kernel<<<dim3(32, 8), 256, 0, stream>>>(ctxb, Wot, (float*)d_out, hidden);
}

// Round 6
// 322.923 us; speedup vs baseline: 1.5959x; 1.0218x over previous
//
#include <hip/hip_runtime.h>

typedef unsigned short u16;
typedef unsigned int u32;
typedef __attribute__((ext_vector_type(4))) float f32x4;
typedef __attribute__((ext_vector_type(8))) short short8;
typedef __attribute__((ext_vector_type(4))) short short4v;

#define BB   2
#define SQL  2048
#define SKVL 4096
#define DM   1024
#define NH   16
#define DK   64
#define L2E  1.44269504f

#if __has_builtin(__builtin_amdgcn_exp2f)
#define EXP2(x) __builtin_amdgcn_exp2f(x)
#else
#define EXP2(x) exp2f(x)
#endif

#define MFMA32(a, b, c) __builtin_amdgcn_mfma_f32_16x16x32_bf16(a, b, c, 0, 0, 0)
#define MFMA16(a, b, c) __builtin_amdgcn_mfma_f32_16x16x16bf16_1k(a, b, c, 0, 0, 0)

__device__ __forceinline__ u16 f2bf(float f) {
  union { float f; unsigned u; } v; v.f = f;
  unsigned r = v.u + 0x7fff + ((v.u >> 16) & 1);   // RNE
  return (u16)(r >> 16);
}

// pack4 via v_perm_b32: hi16(a)|hi16(b)<<16 after round-half-up
__device__ __forceinline__ short4v pack4(float p0, float p1, float p2, float p3) {
  union { float f; u32 u; } a, b, c, d;
  a.f = p0; b.f = p1; c.f = p2; d.f = p3;
  union { uint2 v; short4v s; } r;
  r.v.x = __builtin_amdgcn_perm(b.u + 0x8000u, a.u + 0x8000u, 0x07060302);
  r.v.y = __builtin_amdgcn_perm(d.u + 0x8000u, c.u + 0x8000u, 0x07060302);
  return r.s;
}

// async global->LDS, 16B per lane; lds base wave-uniform, lane i -> base + i*16.
__device__ __forceinline__ void gload16(const void* g, void* lds) {
  __builtin_amdgcn_global_load_lds(
      (const __attribute__((address_space(1))) unsigned int*)g,
      (__attribute__((address_space(3))) unsigned int*)lds, 16, 0, 0);
}

// ---------------- fused preprocessing: rmsnorm | fp32->bf16 cvt | 4x weight transpose ----------------
__global__ void pre_kernel(const float* __restrict__ hidden, const float* __restrict__ lnw,
                           const float* __restrict__ kvs,
                           const float* __restrict__ Wq, const float* __restrict__ Wk,
                           const float* __restrict__ Wv, const float* __restrict__ Wo,
                           u16* __restrict__ normed, u16* __restrict__ kvb,
                           u16* __restrict__ Wqt, u16* __restrict__ Wkt,
                           u16* __restrict__ Wvt, u16* __restrict__ Wot) {
  __shared__ float red[4];
  __shared__ float tile[32][33];
  int bid = blockIdx.x, t = threadIdx.x;
  if (bid < 4096) {
    int row = bid;
    float4 v = ((const float4*)(hidden + (size_t)row * DM))[t];
    float ss = v.x * v.x + v.y * v.y + v.z * v.z + v.w * v.w;
#pragma unroll
    for (int m = 32; m >= 1; m >>= 1) ss += __shfl_xor(ss, m, 64);
    int lane = t & 63, wv = t >> 6;
    if (lane == 0) red[wv] = ss;
    __syncthreads();
    float total = red[0] + red[1] + red[2] + red[3];
    float scale = rsqrtf(total * (1.0f / DM) + 1e-6f);
    float4 g = ((const float4*)lnw)[t];
    ushort4 o;
    o.x = f2bf(v.x * scale * g.x);
    o.y = f2bf(v.y * scale * g.y);
    o.z = f2bf(v.z * scale * g.z);
    o.w = f2bf(v.w * scale * g.w);
    ((ushort4*)(normed + (size_t)row * DM))[t] = o;
  } else if (bid < 12288) {
    int i = (bid - 4096) * 256 + t;
    float4 v = ((const float4*)kvs)[i];
    ushort4 o;
    o.x = f2bf(v.x); o.y = f2bf(v.y); o.z = f2bf(v.z); o.w = f2bf(v.w);
    ((ushort4*)kvb)[i] = o;
  } else {
    int g = bid - 12288;
    int z = g >> 10;
    const float* W = (z == 0) ? Wq : (z == 1) ? Wk : (z == 2) ? Wv : Wo;
    u16* Wt = (z == 0) ? Wqt : (z == 1) ? Wkt : (z == 2) ? Wvt : Wot;
    int xx = g & 31, yy = (g >> 5) & 31;
    int tx = t & 31, ty = t >> 5;
    int k0 = yy * 32, n0 = xx * 32;
#pragma unroll
    for (int i = 0; i < 4; i++)
      tile[ty + i * 8][tx] = W[(size_t)(k0 + ty + i * 8) * DM + n0 + tx];
    __syncthreads();
#pragma unroll
    for (int i = 0; i < 4; i++)
      Wt[(size_t)(n0 + ty + i * 8) * DM + k0 + tx] = f2bf(tile[tx][ty + i * 8]);
  }
}

// ---------------- merged Q/K/V projection, 1280 blocks ----------------
__global__ void proj_kernel(const u16* __restrict__ normed, const u16* __restrict__ kvb,
                            const u16* __restrict__ Wqt, const u16* __restrict__ Wkt,
                            const u16* __restrict__ Wvt,
                            u16* __restrict__ Qb, u16* __restrict__ Kbf,
                            u16* __restrict__ Vtb) {
  const int K = 1024;
  __shared__ __align__(16) u16 Al[128 * 32];
  __shared__ __align__(16) u16 Bl[128 * 32];
  int tid = threadIdx.x, lane = tid & 63, w = tid >> 6;
  int l15 = lane & 15, quad = lane >> 4;
  int wy = w >> 1, wx = w & 1;

  int bid = blockIdx.x;
  int mode;
  const u16 *A, *Bt;
  int tm, tn;
  if (bid < 256) { mode = 0; A = normed; Bt = Wqt; tm = (bid & 31) * 128; tn = (bid >> 5) * 128; }
  else if (bid < 768) { mode = 1; A = kvb; Bt = Wkt; int kid = bid - 256; tm = (kid & 63) * 128; tn = (kid >> 6) * 128; }
  else { mode = 2; A = Wvt; Bt = kvb; int vid = bid - 768; tm = (vid & 7) * 128; tn = (vid >> 3) * 128; }

  f32x4 acc[4][4] = {};
  for (int k0 = 0; k0 < K; k0 += 32) {
    __syncthreads();
#pragma unroll
    for (int r = 0; r < 2; r++) {
      int mg = w * 2 + r;
      gload16(A + (size_t)(tm + mg * 16 + l15) * K + k0 + quad * 8, &Al[mg * 512]);
      gload16(Bt + (size_t)(tn + mg * 16 + l15) * K + k0 + quad * 8, &Bl[mg * 512]);
    }
    __syncthreads();
    short8 af[4], bfr[4];
#pragma unroll
    for (int i = 0; i < 4; i++) {
      af[i] = *(const short8*)&Al[((wy * 4 + i) * 64 + lane) * 8];
      bfr[i] = *(const short8*)&Bl[((wx * 4 + i) * 64 + lane) * 8];
    }
#pragma unroll
    for (int mt = 0; mt < 4; mt++)
#pragma unroll
      for (int nt = 0; nt < 4; nt++)
        acc[mt][nt] = MFMA32(af[mt], bfr[nt], acc[mt][nt]);
  }

#pragma unroll
  for (int mt = 0; mt < 4; mt++) {
    int m0 = tm + wy * 64 + mt * 16 + quad * 4;
#pragma unroll
    for (int nt = 0; nt < 4; nt++) {
      int n = tn + wx * 64 + nt * 16 + l15;
      if (mode == 0) {
#pragma unroll
        for (int r = 0; r < 4; r++)
          Qb[(size_t)(m0 + r) * 1024 + n] = f2bf(acc[mt][nt][r] * L2E);
      } else if (mode == 1) {
#pragma unroll
        for (int r = 0; r < 4; r++)
          Kbf[(size_t)(m0 + r) * 1024 + n] = f2bf(acc[mt][nt][r]);
      } else {
        int b = n >> 12, skv = n & 4095;
        int kvt = skv >> 6, kvl = skv & 63;
        int p = kvl >> 5, kth = (kvl >> 4) & 1, qd = (kvl >> 2) & 3, elo = kvl & 3;
        int e = kth * 4 + elo;
        int h = m0 >> 6, d0 = m0 & 63;
        size_t base = ((size_t)((b * NH + h) * 64 + kvt) << 12) + (size_t)(p * 4 + qd) * 512 + e;
#pragma unroll
        for (int r = 0; r < 4; r++)
          Vtb[base + (size_t)(d0 + r) * 8] = f2bf(acc[mt][nt][r]);
      }
    }
  }
}

// ---------------- flash attention: mask as MFMA C-init, l via MFMA, reg P ----------------
__global__ __launch_bounds__(256, 2) void flash_kernel(
    const u16* __restrict__ Qp, const u16* __restrict__ Kp, const u16* __restrict__ Vtb,
    const float* __restrict__ mask, u16* __restrict__ ctx) {
  __shared__ __align__(16) char smem[65536];
  u16* Kbuf = (u16*)smem;                 // [buf2][grp2][4096]
  u16* Vbuf = (u16*)(smem + 32768);       // [buf2][grp2][4096]
  float* Ox = (float*)smem;               // merge reuse: [128][64]
  float* Ll = (float*)(smem + 32768);     // merge reuse: [128]

  int tid = threadIdx.x, lane = tid & 63, w = tid >> 6;
  int l15 = lane & 15, quad = lane >> 4;
  int grp = w >> 1, wg = w & 1;
  int qb = blockIdx.x, bh = blockIdx.y;
  int b = bh >> 4, h = bh & 15;
  int q0 = qb * 128 + wg * 64;

  short8 qf[4][2];
#pragma unroll
  for (int mt = 0; mt < 4; mt++)
#pragma unroll
    for (int kf = 0; kf < 2; kf++)
      qf[mt][kf] = *(const short8*)(Qp + (size_t)(b * SQL + q0 + mt * 16 + l15) * DM +
                                    h * DK + kf * 32 + quad * 8);

  f32x4 of[4][4] = {};
  f32x4 la[4] = {};
  const short4v ones = {0x3F80, 0x3F80, 0x3F80, 0x3F80};  // bf16 1.0

  const size_t vblob = (size_t)(b * NH + h) * 64 * 4096;
  const float* mrow = mask + (size_t)b * SKVL;

  auto stage = [&](int tileIdx, int buf) {
    int kv0 = tileIdx * 64;
    u16* Kd = Kbuf + (buf * 2 + grp) * 4096;
    u16* Vd = Vbuf + (buf * 2 + grp) * 4096;
#pragma unroll
    for (int r = 0; r < 4; r++) {
      int u = wg * 4 + r;
      int kt = u >> 1, kf = u & 1;
      gload16(Kp + (size_t)(b * SKVL + kv0 + kt * 16 + l15) * DM + h * DK + kf * 32 + quad * 8,
              &Kd[u * 512]);
      gload16(Vtb + vblob + (size_t)tileIdx * 4096 + u * 512 + lane * 8, &Vd[u * 512]);
    }
  };

  // mask prefetch (C-init values): ml[kt] covers kv = tile*64 + kt*16 + quad*4 .. +3
  f32x4 mlc[4], mln[4];
  {
    int kv0 = grp * 64;
#pragma unroll
    for (int kt = 0; kt < 4; kt++)
      mlc[kt] = *(const f32x4*)(mrow + kv0 + kt * 16 + quad * 4) * L2E;
  }
  stage(grp, 0);

  for (int it = 0; it < 32; ++it) {
    __syncthreads();                      // tile it landed (loads issued last iter)
    if (it + 1 < 32) {
      stage((it + 1) * 2 + grp, (it + 1) & 1);
      int kvn = ((it + 1) * 2 + grp) * 64;
#pragma unroll
      for (int kt = 0; kt < 4; kt++)
        mln[kt] = *(const f32x4*)(mrow + kvn + kt * 16 + quad * 4) * L2E;
    }
    const u16* Kg = Kbuf + ((it & 1) * 2 + grp) * 4096;
    const u16* Vg = Vbuf + ((it & 1) * 2 + grp) * 4096;

#pragma unroll
    for (int ktp = 0; ktp < 2; ktp++) {
      short4v pa[2][4];
#pragma unroll
      for (int kth = 0; kth < 2; kth++) {
        int kt = ktp * 2 + kth;
        short8 k0 = *(const short8*)&Kg[((kt * 2 + 0) * 64 + lane) * 8];
        short8 k1 = *(const short8*)&Kg[((kt * 2 + 1) * 64 + lane) * 8];
#pragma unroll
        for (int mt = 0; mt < 4; mt++) {
          f32x4 st = mlc[kt];             // mask*log2e as accumulator init
          st = MFMA32(k0, qf[mt][0], st);
          st = MFMA32(k1, qf[mt][1], st);
          pa[kth][mt] = pack4(EXP2(st[0]), EXP2(st[1]), EXP2(st[2]), EXP2(st[3]));
        }
      }
#pragma unroll
      for (int mt = 0; mt < 4; mt++) {    // l rowsum via matrix pipe
        la[mt] = MFMA16(pa[0][mt], ones, la[mt]);
        la[mt] = MFMA16(pa[1][mt], ones, la[mt]);
      }
#pragma unroll
      for (int nt = 0; nt < 4; nt++) {
        short8 vv = *(const short8*)&Vg[((ktp * 4 + quad) * 64 + nt * 16 + l15) * 8];
        short4v vlo = {vv[0], vv[1], vv[2], vv[3]};
        short4v vhi = {vv[4], vv[5], vv[6], vv[7]};
#pragma unroll
        for (int mt = 0; mt < 4; mt++) {
          of[mt][nt] = MFMA16(pa[0][mt], vlo, of[mt][nt]);
          of[mt][nt] = MFMA16(pa[1][mt], vhi, of[mt][nt]);
        }
      }
    }
#pragma unroll
    for (int kt = 0; kt < 4; kt++) mlc[kt] = mln[kt];
  }

  // merge group partials (additive). la is in C-layout: row q=quad*4+r, cols equal.
  __syncthreads();
  if (grp == 1) {
#pragma unroll
    for (int mt = 0; mt < 4; mt++) {
#pragma unroll
      for (int nt = 0; nt < 4; nt++)
#pragma unroll
        for (int r = 0; r < 4; r++)
          Ox[(wg * 64 + mt * 16 + quad * 4 + r) * 64 + nt * 16 + l15] = of[mt][nt][r];
      if (l15 == 0)
#pragma unroll
        for (int r = 0; r < 4; r++) Ll[wg * 64 + mt * 16 + quad * 4 + r] = la[mt][r];
    }
  }
  __syncthreads();
  if (grp == 0) {
#pragma unroll
    for (int mt = 0; mt < 4; mt++)
#pragma unroll
      for (int r = 0; r < 4; r++) {
        int ql = wg * 64 + mt * 16 + quad * 4 + r;
        float inv = 1.0f / (la[mt][r] + Ll[ql]);
        int q = qb * 128 + ql;
#pragma unroll
        for (int nt = 0; nt < 4; nt++) {
          float ov = of[mt][nt][r] + Ox[ql * 64 + nt * 16 + l15];
          ctx[(size_t)(b * SQL + q) * DM + h * DK + nt * 16 + l15] = f2bf(ov * inv);
        }
      }
  }
}

// ---------------- O projection + residual ----------------
__global__ void ogemm_kernel(const u16* __restrict__ A, const u16* __restrict__ Bt,
                             float* __restrict__ C, const float* __restrict__ resid) {
  const int K = 1024;
  __shared__ __align__(16) u16 Al[128 * 32];
  __shared__ __align__(16) u16 Bl[128 * 32];
  int tid = threadIdx.x, lane = tid & 63, w = tid >> 6;
  int l15 = lane & 15, quad = lane >> 4;
  int wy = w >> 1, wx = w & 1;
  int tm = blockIdx.x * 128, tn = blockIdx.y * 128;
  f32x4 acc[4][4] = {};

  for (int k0 = 0; k0 < K; k0 += 32) {
    __syncthreads();
#pragma unroll
    for (int r = 0; r < 2; r++) {
      int mg = w * 2 + r;
      gload16(A + (size_t)(tm + mg * 16 + l15) * K + k0 + quad * 8, &Al[mg * 512]);
      gload16(Bt + (size_t)(tn + mg * 16 + l15) * K + k0 + quad * 8, &Bl[mg * 512]);
    }
    __syncthreads();
    short8 af[4], bfr[4];
#pragma unroll
    for (int i = 0; i < 4; i++) {
      af[i] = *(const short8*)&Al[((wy * 4 + i) * 64 + lane) * 8];
      bfr[i] = *(const short8*)&Bl[((wx * 4 + i) * 64 + lane) * 8];
    }
#pragma unroll
    for (int mt = 0; mt < 4; mt++)
#pragma unroll
      for (int nt = 0; nt < 4; nt++)
        acc[mt][nt] = MFMA32(af[mt], bfr[nt], acc[mt][nt]);
  }

#pragma unroll
  for (int mt = 0; mt < 4; mt++) {
    int m0 = tm + wy * 64 + mt * 16 + quad * 4;
#pragma unroll
    for (int nt = 0; nt < 4; nt++) {
      int n = tn + wx * 64 + nt * 16 + l15;
#pragma unroll
      for (int r = 0; r < 4; r++) {
        size_t idx = (size_t)(m0 + r) * 1024 + n;
        C[idx] = resid[idx] + acc[mt][nt][r];
      }
    }
  }
}

extern "C" void kernel_launch(void* const* d_in, const int* in_sizes, int n_in,
                              void* d_out, int out_size, void* d_ws, size_t ws_size,
                              hipStream_t stream) {
  const float* hidden = (const float*)d_in[0];
  const float* kvs    = (const float*)d_in[1];
  const float* mask   = (const float*)d_in[2];
  const float* lnw    = (const float*)d_in[3];
  const float* Wq     = (const float*)d_in[4];
  const float* Wk     = (const float*)d_in[5];
  const float* Wv     = (const float*)d_in[6];
  const float* Wo     = (const float*)d_in[7];
  char* ws = (char*)d_ws;

  u16* normed = (u16*)(ws + 0);           // 8 MB
  u16* kvb    = (u16*)(ws + 8388608);     // 16 MB
  u16* Wqt    = (u16*)(ws + 25165824);    // 2 MB
  u16* Wkt    = (u16*)(ws + 27262976);    // 2 MB
  u16* Wvt    = (u16*)(ws + 29360128);    // 2 MB
  u16* Wot    = (u16*)(ws + 31457280);    // 2 MB
  u16* Qb     = (u16*)(ws + 33554432);    // 8 MB (pre-scaled by log2e)
  u16* Kbf    = (u16*)(ws + 41943040);    // 16 MB
  u16* Vtb    = (u16*)(ws + 58720256);    // 16 MB (blob layout)
  u16* ctxb   = (u16*)(ws + 75497472);    // 8 MB

  pre_kernel<<<16384, 256, 0, stream>>>(hidden, lnw, kvs, Wq, Wk, Wv, Wo,
                                        normed, kvb, Wqt, Wkt, Wvt, Wot);
  proj_kernel<<<1280, 256, 0, stream>>>(normed, kvb, Wqt, Wkt, Wvt, Qb, Kbf, Vtb);
  flash_kernel<<<dim3(SQL / 128, BB * NH), 256, 0, stream>>>(Qb, Kbf, Vtb, mask, ctxb);
  ogemm_kernel<<<dim3(32, 8), 256, 0, stream>>>(ctxb, Wot, (float*)d_out, hidden);
}